// Round 1
// baseline (274.114 us; speedup 1.0000x reference)
//
#include <hip/hip_runtime.h>

typedef __attribute__((ext_vector_type(8))) short short8;
typedef __attribute__((ext_vector_type(4))) float f32x4;

__device__ __forceinline__ unsigned short f32_to_bf16(float f) {
    union { float f; unsigned int u; } c; c.f = f;
    unsigned int u = c.u;
    // round-to-nearest-even
    unsigned int r = (u + 0x7fffu + ((u >> 16) & 1u)) >> 16;
    return (unsigned short)r;
}

// Normalize rows of [nrows, 128] fp32 -> bf16 rows scaled by 3/||v||, plus
// sq-norm output xs[row] = 9*sq*r^2 (== sum(x*x) to ~1e-6).
// One wave per row, 4 waves per block.
__global__ void norm_kernel(const float* __restrict__ in,
                            unsigned short* __restrict__ xout,
                            float* __restrict__ sout) {
    const int row  = blockIdx.x * 4 + (threadIdx.x >> 6);
    const int lane = threadIdx.x & 63;
    const float2 v = ((const float2*)(in + (size_t)row * 128))[lane];
    float s = fmaf(v.x, v.x, v.y * v.y);
#pragma unroll
    for (int off = 32; off; off >>= 1) s += __shfl_xor(s, off, 64);
    const float r  = rsqrtf(fmaxf(s, 1e-12f));
    const float sc = 3.0f * r;
    ushort2 o;
    o.x = f32_to_bf16(v.x * sc);
    o.y = f32_to_bf16(v.y * sc);
    ((ushort2*)(xout + (size_t)row * 128))[lane] = o;
    if (lane == 0) sout[row] = 9.0f * s * (r * r);
}

// C = xs[b] + ps[c] - 2 * A*B^T, A:[M,128] bf16 row-major, B:[N,128] bf16 row-major.
// 128x128 output tile per block, full K=128 staged in LDS once.
// Staging via global_load_lds (16B/lane, lane-linear LDS dest). 16B chunks are
// XOR-swizzled within each row (jj = j ^ (m&7)) so the mfma fragment
// ds_read_b128s are only 2-way bank-aliased (free on CDNA4).
__global__ __launch_bounds__(256, 2) void gemm_kernel(
    const unsigned short* __restrict__ A,
    const unsigned short* __restrict__ B,
    const float* __restrict__ xs,
    const float* __restrict__ ps,
    float* __restrict__ out,
    int Ncols)
{
    __shared__ unsigned short sA[128 * 128];  // 32 KB
    __shared__ unsigned short sB[128 * 128];  // 32 KB

    const int tid  = threadIdx.x;
    const int lane = tid & 63;
    const int wave = tid >> 6;
    const int bm   = blockIdx.y;
    const int bn   = blockIdx.x;

    const int wm   = (wave >> 1) * 64;  // wave's row offset in tile
    const int wn   = (wave & 1) * 64;   // wave's col offset in tile
    const int l15  = lane & 15;
    const int quad = lane >> 4;

    // Preload xs/ps for this lane's epilogue elements (registers, not LDS —
    // keeps static LDS at exactly 64KB). These L1/L2-hit loads issue early.
    float xsr[16];
    float psr[4];
#pragma unroll
    for (int mt = 0; mt < 4; ++mt)
#pragma unroll
        for (int r = 0; r < 4; ++r)
            xsr[mt * 4 + r] = xs[bm * 128 + wm + mt * 16 + quad * 4 + r];
#pragma unroll
    for (int nt = 0; nt < 4; ++nt)
        psr[nt] = ps[bn * 128 + wn + nt * 16 + l15];

    // --- stage A and B tiles: 2048 x 16B chunks each, 8 iters x 256 threads
    {
        const char* gA = (const char*)(A + (size_t)bm * 128 * 128);
        const char* gB = (const char*)(B + (size_t)bn * 128 * 128);
#pragma unroll
        for (int it = 0; it < 8; ++it) {
            const int cid = it * 256 + wave * 64 + lane;  // linear 16B-chunk id
            const int m   = cid >> 4;                      // row in tile
            const int jj  = cid & 15;                      // LDS chunk slot
            const int gj  = jj ^ (m & 7);                  // swizzled global chunk
            const int gbyte = m * 256 + gj * 16;
            const int lbyte = cid * 16;
            __builtin_amdgcn_global_load_lds(
                (const __attribute__((address_space(1))) void*)(gA + gbyte),
                (__attribute__((address_space(3))) void*)((char*)sA + lbyte),
                16, 0, 0);
            __builtin_amdgcn_global_load_lds(
                (const __attribute__((address_space(1))) void*)(gB + gbyte),
                (__attribute__((address_space(3))) void*)((char*)sB + lbyte),
                16, 0, 0);
        }
    }
    __syncthreads();  // compiler drains vmcnt before s_barrier

    f32x4 acc[4][4];
#pragma unroll
    for (int i = 0; i < 4; ++i)
#pragma unroll
        for (int j = 0; j < 4; ++j)
            acc[i][j] = (f32x4){0.f, 0.f, 0.f, 0.f};

    // K = 128 -> 4 MFMA k-steps of 32
#pragma unroll
    for (int kk = 0; kk < 4; ++kk) {
        short8 af[4], bfv[4];
#pragma unroll
        for (int mt = 0; mt < 4; ++mt) {
            const int m  = wm + mt * 16 + l15;
            const int jj = (kk * 4 + quad) ^ (m & 7);
            af[mt] = *(const short8*)&sA[m * 128 + jj * 8];
        }
#pragma unroll
        for (int nt = 0; nt < 4; ++nt) {
            const int n  = wn + nt * 16 + l15;
            const int jj = (kk * 4 + quad) ^ (n & 7);
            bfv[nt] = *(const short8*)&sB[n * 128 + jj * 8];
        }
#pragma unroll
        for (int mt = 0; mt < 4; ++mt)
#pragma unroll
            for (int nt = 0; nt < 4; ++nt)
                acc[mt][nt] = __builtin_amdgcn_mfma_f32_16x16x32_bf16(
                    af[mt], bfv[nt], acc[mt][nt], 0, 0, 0);
    }

    // --- epilogue: out = xs[b] + ps[c] - 2*dot
    const size_t stride = (size_t)Ncols;
#pragma unroll
    for (int mt = 0; mt < 4; ++mt) {
        const int rl   = wm + mt * 16 + quad * 4;     // local row base (reg dim)
        const int grow = bm * 128 + rl;
#pragma unroll
        for (int nt = 0; nt < 4; ++nt) {
            const int gcol = bn * 128 + wn + nt * 16 + l15;
            const float pv = psr[nt];
            float* op = out + (size_t)grow * stride + gcol;
#pragma unroll
            for (int r = 0; r < 4; ++r) {
                op[(size_t)r * stride] =
                    fmaf(-2.0f, acc[mt][nt][r], xsr[mt * 4 + r] + pv);
            }
        }
    }
}

extern "C" void kernel_launch(void* const* d_in, const int* in_sizes, int n_in,
                              void* d_out, int out_size, void* d_ws, size_t ws_size,
                              hipStream_t stream) {
    const float* inputs = (const float*)d_in[0];
    const float* kern   = (const float*)d_in[1];
    float* out          = (float*)d_out;

    const int D = 128;
    const int B = in_sizes[0] / D;   // 4096
    const int C = in_sizes[1] / D;   // 16384

    char* ws = (char*)d_ws;
    unsigned short* xA = (unsigned short*)ws;                       // B*D bf16
    unsigned short* pB = (unsigned short*)(ws + (size_t)B * D * 2); // C*D bf16
    float* xs = (float*)(ws + (size_t)(B + C) * D * 2);             // B floats
    float* ps = xs + B;                                             // C floats

    norm_kernel<<<B / 4, 256, 0, stream>>>(inputs, xA, xs);
    norm_kernel<<<C / 4, 256, 0, stream>>>(kern, pB, ps);

    dim3 grid(C / 128, B / 128);  // 128 x 32 = 4096 blocks
    gemm_kernel<<<grid, 256, 0, stream>>>(xA, pB, xs, ps, out, C);
}